// Round 10
// baseline (73.138 us; speedup 1.0000x reference)
//
#include <hip/hip_runtime.h>
#include <hip/hip_fp16.h>

typedef __bf16 bf16x8 __attribute__((ext_vector_type(8)));
typedef float floatx16 __attribute__((ext_vector_type(16)));
typedef unsigned int uint;
typedef unsigned short ushort;
typedef uint  uintx4  __attribute__((ext_vector_type(4)));
typedef float floatx4 __attribute__((ext_vector_type(4)));

constexpr int Mdim = 256, Ndim = 8192, Kdim = 8192;
constexpr int BN = 64, KSPLIT = 4;
constexpr int KS = Kdim / KSPLIT;    // 2048 k per block
constexpr int NT = KS / 64;          // 32 64k-steps (2 per barrier phase)
constexpr int KB = Kdim / 256;       // 32 superblocks per weight row

union U8 { uint u[4]; bf16x8 v; };

__device__ __forceinline__ uint cvtpk(float lo, float hi) {
  uint r; asm("v_cvt_pk_bf16_f32 %0, %1, %2" : "=v"(r) : "v"(lo), "v"(hi));
  return r;
}

// explicit global (addrspace(1)) loads: guaranteed global_load_* (vmcnt-only)
template <typename T>
__device__ __forceinline__ T gld(const void* p) {
  return *(const __attribute__((address_space(1))) T*)p;
}

// async global->LDS, 16B per lane; LDS dest = wave-uniform base + lane*16
__device__ __forceinline__ void glds16(const void* g, void* l) {
  __builtin_amdgcn_global_load_lds(
      (const __attribute__((address_space(1))) uint*)g,
      (__attribute__((address_space(3))) uint*)l, 16, 0, 0);
}

// bf16 B LDS: 64 rows x 128 ushort; 16 chunks of 16B, XOR-swizzled (R9-verified)
__device__ __forceinline__ int bswz(int row, int ch) {
  return row * 128 + ((ch ^ (row & 15)) << 3);
}

#define WAITVM_(n) asm volatile("s_waitcnt vmcnt(" #n ")" ::: "memory")
#define WAITVM(n) WAITVM_(n)
#define NOWAIT ((void)0)
#define S6(s) ((s) % 6)

template<bool PRE>
__global__ __launch_bounds__(256, 2)
void q4k_gemm(const float* __restrict__ x, const bf16x8* __restrict__ xbf,
              const int* __restrict__ qw, const float* __restrict__ bias,
              float* __restrict__ out)
{
  // 48 KB raw-qs ring (6 slots x 64 rows x 32 ints) + 32 KB bf16 double buffer
  __shared__ __align__(16) int Qs[6 * 2048];
  __shared__ ushort Bb[2][BN * 128];

  const int tid = threadIdx.x;
  const int bid = blockIdx.x;
  // bijective XCD swizzle (512 blocks): ks-siblings of one n-tile co-XCD
  const int l  = (bid & 7) * 64 + (bid >> 3);
  const int nb = l >> 2;              // 0..127
  const int ks = l & 3;
  const int n0 = nb * BN;
  const int ks8 = ks * (KS >> 8);

  const int sr = tid >> 2;   // dequant row 0..63
  const int sq = tid & 3;    // 8-int slice within the 32-int qs region

  const int lane = tid & 63;
  const int wave = tid >> 6;
  const int mb0  = wave * 2;          // two 32-row m-frags per wave
  const int brow = lane & 31;
  const int bco  = lane >> 5;

  const int* bp0 = qw + (n0 + sr) * (KB * 144);
  const bf16x8* xA0 = PRE ? (xbf + ((mb0    ) * 512 + ks * 128) * 64 + lane) : nullptr;
  const bf16x8* xA1 = PRE ? (xbf + ((mb0 + 1) * 512 + ks * 128) * 64 + lane) : nullptr;

  uintx4 Mdd[2], M0[2], M1[2], M2[2];    // meta: 2 superblock slots (registers)
  U8 pqL, pqH;
  bf16x8 aA[8], aB[8];
  floatx16 acc00 = {}, acc01 = {}, acc10 = {}, acc11 = {};

  // DMA step s's raw qs (64 rows x 128B) into ring slot: linear LDS, source
  // pre-swizzled so that LDS[row][cpos] = global chunk (cpos ^ (row&7)).
  auto stageQ = [&](int s, int slot) {
    const int sb = s >> 2, c64 = s & 3;
    const int schk = ((lane & 7) ^ (lane >> 3)) << 2;   // pre-swizzled src chunk
    #pragma unroll
    for (int j = 0; j < 2; ++j) {
      const int r = j * 32 + wave * 8 + (lane >> 3);
      const int* src = qw + (n0 + r) * (KB * 144) + (ks8 + sb) * 144
                       + 16 + c64 * 32 + schk;
      glds16((const void*)src, (void*)&Qs[slot * 2048 + (j * 256 + wave * 64) * 4]);
    }
  };

  auto mload = [&](int sbrel, int ms) {
    const int* bp = bp0 + (ks8 + sbrel) * 144;
    Mdd[ms] = gld<uintx4>(bp);
    M0[ms]  = gld<uintx4>(bp + 4);
    M1[ms]  = gld<uintx4>(bp + 8);
    M2[ms]  = gld<uintx4>(bp + 12);
  };

  auto gloadA = [&](int t, bf16x8 (&A)[8]) {
    if constexpr (PRE) {
      const int f = t * 4 * 64;
      #pragma unroll
      for (int kk = 0; kk < 4; ++kk) {
        A[kk]     = gld<bf16x8>(xA0 + f + kk * 64);
        A[4 + kk] = gld<bf16x8>(xA1 + f + kk * 64);
      }
    } else {
      const int kg = ks * KS + t * 64 + bco * 8;
      #pragma unroll
      for (int kk = 0; kk < 4; ++kk) {
        const float* fA = x + (mb0 * 32 + brow) * Kdim + kg + kk * 16;
        const float* fB = x + ((mb0 + 1) * 32 + brow) * Kdim + kg + kk * 16;
        const floatx4 p0 = gld<floatx4>(fA), p1 = gld<floatx4>(fA + 4);
        const floatx4 q0 = gld<floatx4>(fB), q1 = gld<floatx4>(fB + 4);
        U8 ua, ub;
        ua.u[0] = cvtpk(p0.x, p0.y); ua.u[1] = cvtpk(p0.z, p0.w);
        ua.u[2] = cvtpk(p1.x, p1.y); ua.u[3] = cvtpk(p1.z, p1.w);
        ub.u[0] = cvtpk(q0.x, q0.y); ub.u[1] = cvtpk(q0.z, q0.w);
        ub.u[2] = cvtpk(q1.x, q1.y); ub.u[3] = cvtpk(q1.z, q1.w);
        A[kk] = ua.v; A[4 + kk] = ub.v;
      }
    }
  };

  // dequant thread slice: row sr, ints [sq*8, sq*8+8) = chunks 2sq, 2sq+1
  auto dequant = [&](int c, int slot, int ms) {
    const int* qrow = &Qs[slot * 2048 + sr * 32];
    const uintx4 q0 = *(const uintx4*)(qrow + ((( 2 * sq)     ^ (sr & 7)) << 2));
    const uintx4 q1 = *(const uintx4*)(qrow + ((( 2 * sq + 1) ^ (sr & 7)) << 2));
    const uintx4 dd = Mdd[ms];
    const float d  = __half2float(__ushort_as_half((ushort)((dd.x & 255u) | ((dd.y & 255u) << 8))));
    const float dm = __half2float(__ushort_as_half((ushort)((dd.z & 255u) | ((dd.w & 255u) << 8))));
    const uintx4 s0 = M0[ms], s1 = M1[ms], s2 = M2[ms];
    uint scA, scB, mnA, mnB;
    if (c == 0)      { scA = s0.x & 63u; scB = s0.y & 63u; mnA = s1.x & 63u; mnB = s1.y & 63u; }
    else if (c == 1) { scA = s0.z & 63u; scB = s0.w & 63u; mnA = s1.z & 63u; mnB = s1.w & 63u; }
    else if (c == 2) {
      scA = (s2.x & 15u) | ((s0.x >> 2) & 48u); scB = (s2.y & 15u) | ((s0.y >> 2) & 48u);
      mnA = (s2.x >> 4)  | ((s1.x >> 2) & 48u); mnB = (s2.y >> 4)  | ((s1.y >> 2) & 48u);
    } else {
      scA = (s2.z & 15u) | ((s0.z >> 2) & 48u); scB = (s2.w & 15u) | ((s0.w >> 2) & 48u);
      mnA = (s2.z >> 4)  | ((s1.z >> 2) & 48u); mnB = (s2.w >> 4)  | ((s1.w >> 2) & 48u);
    }
    const float dlA = d * (float)scA, mlA = dm * (float)mnA;
    const float dlB = d * (float)scB, mlB = dm * (float)mnB;
    float wl[8], wh[8];
    #pragma unroll
    for (int h = 0; h < 2; ++h) {
      const uintx4 qv = h ? q1 : q0;
      wl[h*4+0] = fmaf(dlA, (float)(qv.x & 15u), -mlA);
      wl[h*4+1] = fmaf(dlA, (float)(qv.y & 15u), -mlA);
      wl[h*4+2] = fmaf(dlA, (float)(qv.z & 15u), -mlA);
      wl[h*4+3] = fmaf(dlA, (float)(qv.w & 15u), -mlA);
      wh[h*4+0] = fmaf(dlB, (float)(qv.x >> 4), -mlB);
      wh[h*4+1] = fmaf(dlB, (float)(qv.y >> 4), -mlB);
      wh[h*4+2] = fmaf(dlB, (float)(qv.z >> 4), -mlB);
      wh[h*4+3] = fmaf(dlB, (float)(qv.w >> 4), -mlB);
    }
    #pragma unroll
    for (int p = 0; p < 4; ++p) {
      pqL.u[p] = cvtpk(wl[2*p], wl[2*p+1]);
      pqH.u[p] = cvtpk(wh[2*p], wh[2*p+1]);
    }
  };

  auto bwrite = [&](int bufi, int h) {
    *(bf16x8*)&Bb[bufi][bswz(sr, h * 8 + sq)]     = pqL.v;
    *(bf16x8*)&Bb[bufi][bswz(sr, h * 8 + 4 + sq)] = pqH.v;
  };

  auto mstep = [&](int bufi, int h, const bf16x8 (&A)[8]) {
    #pragma unroll
    for (int kk = 0; kk < 4; ++kk) {
      const bf16x8 bq0 = *(const bf16x8*)&Bb[bufi][bswz(brow,      h * 8 + kk * 2 + bco)];
      const bf16x8 bq1 = *(const bf16x8*)&Bb[bufi][bswz(brow + 32, h * 8 + kk * 2 + bco)];
      acc00 = __builtin_amdgcn_mfma_f32_32x32x16_bf16(A[kk],     bq0, acc00, 0, 0, 0);
      acc01 = __builtin_amdgcn_mfma_f32_32x32x16_bf16(A[kk],     bq1, acc01, 0, 0, 0);
      acc10 = __builtin_amdgcn_mfma_f32_32x32x16_bf16(A[4 + kk], bq0, acc10, 0, 0, 0);
      acc11 = __builtin_amdgcn_mfma_f32_32x32x16_bf16(A[4 + kk], bq1, acc11, 0, 0, 0);
    }
  };

  // ---------------- prologue ----------------
  // DMA steps 0..3, meta sb0/sb1, A steps 0/1, DMA steps 4..5 (LAST).
  stageQ(0, 0); stageQ(1, 1);          // batch {0,1}: 4 DMA
  stageQ(2, 2); stageQ(3, 3);          // batch {2,3}: 4 DMA
  mload(0, 0); mload(1, 1);            // 8 loads
  gloadA(0, aA); gloadA(1, aB);        // 16 loads
  stageQ(4, 4); stageQ(5, 5);          // batch {4,5}: 4 DMA
  WAITVM(32);                          // certify batch {0,1}: 4+8+16+4 after
  __builtin_amdgcn_s_barrier();
  dequant(0, 0, 0); bwrite(0, 0);
  dequant(1, 1, 0); bwrite(0, 1);
  WAITVM(28);                          // certify batch {2,3}: 8+16+4 after
  asm volatile("s_waitcnt lgkmcnt(0)" ::: "memory");
  __builtin_amdgcn_s_barrier();
  __builtin_amdgcn_sched_barrier(0);

  // ---------------- 16 phases ----------------
  // phase P: (a) dequant steps {2P+2,2P+3} (slots certified 1 barrier ago)
  //          (b) DMA steps {2P+6,2P+7}  (c) meta (odd P, 2-sb cover)
  //          (e) 2x mstep + A refill  (f) counted vmcnt certifying P-1's DMA
  //          (g) lgkmcnt(0) + barrier.  vmcnt never drains in-loop.
  #define MG(P) (((P) + 3) / 2 > 7 ? 7 : ((P) + 3) / 2)
  #define PH(P, WAITSTMT) {                                                  \
    if ((2*(P)+3) < NT) {                                                    \
      dequant((2*(P)+2) & 3, S6(2*(P)+2), ((2*(P)+2) >> 2) & 1);             \
      bwrite(((P)+1) & 1, 0);                                                \
      dequant((2*(P)+3) & 3, S6(2*(P)+3), ((2*(P)+3) >> 2) & 1);             \
      bwrite(((P)+1) & 1, 1);                                                \
    }                                                                        \
    if ((P) <= 12) { stageQ(2*(P)+6, S6(2*(P)+6)); stageQ(2*(P)+7, S6(2*(P)+7)); } \
    if (((P) & 1) && (P) <= 13) mload(MG(P), MG(P) & 1);                     \
    __builtin_amdgcn_s_setprio(1);                                           \
    mstep((P) & 1, 0, aA);                                                   \
    __builtin_amdgcn_s_setprio(0);                                           \
    if ((2*(P)+2) < NT) gloadA(2*(P)+2, aA);                                 \
    __builtin_amdgcn_s_setprio(1);                                           \
    mstep((P) & 1, 1, aB);                                                   \
    __builtin_amdgcn_s_setprio(0);                                           \
    if ((2*(P)+3) < NT) gloadA(2*(P)+3, aB);                                 \
    WAITSTMT;                                                                \
    asm volatile("s_waitcnt lgkmcnt(0)" ::: "memory");                       \
    __builtin_amdgcn_s_barrier();                                            \
    __builtin_amdgcn_sched_barrier(0);                                       \
  }

  PH(0,  WAITVM(20))
  PH(1,  WAITVM(40)) PH(2,  WAITVM(40)) PH(3,  WAITVM(40)) PH(4,  WAITVM(40))
  PH(5,  WAITVM(40)) PH(6,  WAITVM(40)) PH(7,  WAITVM(40)) PH(8,  WAITVM(40))
  PH(9,  WAITVM(40)) PH(10, WAITVM(40)) PH(11, WAITVM(40)) PH(12, WAITVM(40))
  PH(13, WAITVM(36))
  PH(14, NOWAIT)
  PH(15, NOWAIT)
  #undef PH
  #undef MG

  // epilogue: D layout col=lane&31, row=(r&3)+8*(r>>2)+4*(lane>>5)  [m74/m101]
  const int gn0 = n0 + (lane & 31);
  const int gn1 = gn0 + 32;
  const float bv0 = (ks == 0) ? bias[gn0] : 0.0f;
  const float bv1 = (ks == 0) ? bias[gn1] : 0.0f;
  const int mrow = wave * 64 + 4 * (lane >> 5);
  #pragma unroll
  for (int r = 0; r < 16; ++r) {
    const int m = mrow + (r & 3) + 8 * (r >> 2);
    atomicAdd(&out[m * Ndim + gn0], acc00[r] + bv0);
    atomicAdd(&out[m * Ndim + gn1], acc01[r] + bv1);
    atomicAdd(&out[(m + 32) * Ndim + gn0], acc10[r] + bv0);
    atomicAdd(&out[(m + 32) * Ndim + gn1], acc11[r] + bv1);
  }
}

// zero d_out (atomic accumulate target) and optionally pre-tile x -> bf16
// MFMA-fragment layout: xb[(mb*512+kb)*64+lane] = 16B frag slice,
// m = mb*32+(lane&31), k = kb*16+(lane>>5)*8
template<bool DOCVT>
__global__ __launch_bounds__(256)
void prep(const float* __restrict__ x, uintx4* __restrict__ xb,
          floatx4* __restrict__ out)
{
  const int gid = blockIdx.x * 256 + threadIdx.x;
  out[gid * 2]     = floatx4{0.f, 0.f, 0.f, 0.f};
  out[gid * 2 + 1] = floatx4{0.f, 0.f, 0.f, 0.f};
  if (DOCVT) {
    const int lane = gid & 63;
    const int m = ((gid >> 15) * 32) + (lane & 31);
    const int k = (((gid >> 6) & 511) * 16) + (lane >> 5) * 8;
    const floatx4 f0 = gld<floatx4>(x + m * Kdim + k);
    const floatx4 f1 = gld<floatx4>(x + m * Kdim + k + 4);
    uintx4 st;
    st.x = cvtpk(f0.x, f0.y); st.y = cvtpk(f0.z, f0.w);
    st.z = cvtpk(f1.x, f1.y); st.w = cvtpk(f1.z, f1.w);
    xb[gid] = st;
  }
}

extern "C" void kernel_launch(void* const* d_in, const int* in_sizes, int n_in,
                              void* d_out, int out_size, void* d_ws, size_t ws_size,
                              hipStream_t stream) {
  (void)in_sizes; (void)n_in; (void)out_size;
  const float* x    = (const float*)d_in[0];
  const int*   qw   = (const int*)d_in[1];
  const float* bias = (const float*)d_in[2];
  float* out = (float*)d_out;

  const size_t need = (size_t)Mdim * Kdim * 2;   // 4 MB bf16 fragment tiles
  if (ws_size >= need) {
    prep<true><<<1024, 256, 0, stream>>>(x, (uintx4*)d_ws, (floatx4*)out);
    q4k_gemm<true><<<512, 256, 0, stream>>>(x, (const bf16x8*)d_ws, qw, bias, out);
  } else {
    prep<false><<<1024, 256, 0, stream>>>(x, nullptr, (floatx4*)out);
    q4k_gemm<false><<<512, 256, 0, stream>>>(x, nullptr, qw, bias, out);
  }
}